// Round 3
// baseline (710.145 us; speedup 1.0000x reference)
//
#include <hip/hip_runtime.h>

typedef __attribute__((ext_vector_type(4))) float f32x4;
typedef __attribute__((ext_vector_type(8))) short bf16x8;
typedef __attribute__((ext_vector_type(4))) unsigned int uint4v;
typedef __attribute__((ext_vector_type(4))) unsigned short ushort4v;
typedef unsigned short u16;
typedef unsigned int u32;

#define AS1(p) ((const __attribute__((address_space(1))) u32*)(p))
#define AS3(p) ((__attribute__((address_space(3))) u32*)(p))

__device__ __forceinline__ float bf2f(u16 v) {
    u32 u = ((u32)v) << 16;
    return __builtin_bit_cast(float, u);
}
__device__ __forceinline__ u16 f2bf(float f) {
    u32 u = __builtin_bit_cast(u32, f);
    u += 0x7fffu + ((u >> 16) & 1u);   // RNE
    return (u16)(u >> 16);
}

// ---------------------------------------------------------------- convert x
__global__ __launch_bounds__(256) void k_cvt_bf16(const float* __restrict__ in,
                                                  u16* __restrict__ out, int n8) {
    int t = blockIdx.x * 256 + threadIdx.x;
    if (t >= n8) return;
    const f32x4* p = (const f32x4*)in + (size_t)t * 2;
    f32x4 a = p[0], b = p[1];
    uint4v o;
    o[0] = (u32)f2bf(a[0]) | ((u32)f2bf(a[1]) << 16);
    o[1] = (u32)f2bf(a[2]) | ((u32)f2bf(a[3]) << 16);
    o[2] = (u32)f2bf(b[0]) | ((u32)f2bf(b[1]) << 16);
    o[3] = (u32)f2bf(b[2]) | ((u32)f2bf(b[3]) << 16);
    *((uint4v*)(out + (size_t)t * 8)) = o;
}

// ------------------------------------------- transpose-convert W -> W^T bf16
__global__ __launch_bounds__(256) void k_transpose_bf16(const float* __restrict__ in,
                                                        u16* __restrict__ out,
                                                        int R, int C) {
    __shared__ float tile[32][33];
    const int bx = blockIdx.x * 32, by = blockIdx.y * 32;
    const int tx = threadIdx.x & 31, ty = threadIdx.x >> 5;   // 256 threads
#pragma unroll
    for (int i = 0; i < 32; i += 8)
        tile[ty + i][tx] = in[(size_t)(by + ty + i) * C + bx + tx];
    __syncthreads();
#pragma unroll
    for (int i = 0; i < 32; i += 8)
        out[(size_t)(bx + ty + i) * R + by + tx] = f2bf(tile[tx][ty + i]);
}

// ----------------------------------------------------- GEMM  C = A * B^T + b
// A: [M][K] bf16, Bt: [N][K] bf16, bias[N] f32. 128x128 tile, BK=32, 4 waves.
template <int OUT_BF16>
__global__ __launch_bounds__(256) void k_gemm_bt(const u16* __restrict__ A,
                                                 const u16* __restrict__ Bt,
                                                 const float* __restrict__ bias,
                                                 void* __restrict__ Cout,
                                                 int M, int N, int K) {
    __shared__ u16 As[128][32];
    __shared__ u16 Bs[128][32];
    const int w = threadIdx.x >> 6, l = threadIdx.x & 63;
    const int lr = l & 15, lg = l >> 4;
    const size_t brow = (size_t)blockIdx.x * 128, bcol = (size_t)blockIdx.y * 128;
    const int wm = (w >> 1) * 64, wn = (w & 1) * 64;

    f32x4 acc[4][4];
#pragma unroll
    for (int i = 0; i < 4; ++i)
#pragma unroll
        for (int j = 0; j < 4; ++j) acc[i][j] = (f32x4){0.f, 0.f, 0.f, 0.f};

    // staging: chunks 2w,2w+1 of 16 rows each; XOR slot swizzle on source
    const int srow = w * 32 + (l >> 2);
    const int scol = ((l & 3) ^ ((l >> 3) & 3)) * 8;
    const u16* ga = A + ((size_t)brow + srow) * K + scol;
    const u16* gb = Bt + ((size_t)bcol + srow) * K + scol;
    u16* lA = &As[w * 32][0];
    u16* lB = &Bs[w * 32][0];
    const int rslot = (lg ^ ((lr >> 1) & 3)) * 8;   // swizzled read slot

    for (int k0 = 0; k0 < K; k0 += 32) {
        __syncthreads();
        __builtin_amdgcn_global_load_lds(AS1(ga + k0), AS3(lA), 16, 0, 0);
        __builtin_amdgcn_global_load_lds(AS1(ga + (size_t)16 * K + k0), AS3(lA + 512), 16, 0, 0);
        __builtin_amdgcn_global_load_lds(AS1(gb + k0), AS3(lB), 16, 0, 0);
        __builtin_amdgcn_global_load_lds(AS1(gb + (size_t)16 * K + k0), AS3(lB + 512), 16, 0, 0);
        __syncthreads();
        bf16x8 af[4], bff[4];
#pragma unroll
        for (int i = 0; i < 4; ++i) {
            af[i]  = *(const bf16x8*)&As[wm + i * 16 + lr][rslot];
            bff[i] = *(const bf16x8*)&Bs[wn + i * 16 + lr][rslot];
        }
#pragma unroll
        for (int i = 0; i < 4; ++i)
#pragma unroll
            for (int j = 0; j < 4; ++j)
                acc[i][j] = __builtin_amdgcn_mfma_f32_16x16x32_bf16(af[i], bff[j], acc[i][j], 0, 0, 0);
    }

#pragma unroll
    for (int i = 0; i < 4; ++i) {
        const size_t row0 = brow + wm + i * 16 + lg * 4;
#pragma unroll
        for (int j = 0; j < 4; ++j) {
            const size_t col = bcol + wn + j * 16 + lr;
            const float bv = bias[col];
#pragma unroll
            for (int r = 0; r < 4; ++r) {
                float v = acc[i][j][r] + bv;
                if (OUT_BF16)
                    ((u16*)Cout)[(row0 + r) * N + col] = f2bf(v);
                else
                    ((float*)Cout)[(row0 + r) * N + col] = v;
            }
        }
    }
}

// ------------------------------------------------------------------- RoPE
// qkv[b][s][6144] bf16 -> qb/kb [b][h][s][128] bf16 (rope applied)
__global__ __launch_bounds__(256) void k_rope(const u16* __restrict__ qkv,
                                              const float* __restrict__ fcos,
                                              const float* __restrict__ fsin,
                                              u16* __restrict__ qb, u16* __restrict__ kb) {
    const int t = blockIdx.x * 256 + threadIdx.x;
    const int e = t & 7, h = (t >> 3) & 15, r = (t >> 7) & 1, s = (t >> 8) & 2047, b = t >> 19;
    const u16* src = qkv + ((size_t)(b * 2048 + s)) * 6144 + r * 2048 + h * 128 + e * 16;
    uint4v p0 = *(const uint4v*)src;
    uint4v p1 = *(const uint4v*)(src + 8);
    const float* cp = fcos + s * 64 + e * 8;
    const float* sp = fsin + s * 64 + e * 8;
    f32x4 c0 = *(const f32x4*)cp, c1 = *(const f32x4*)(cp + 4);
    f32x4 s0 = *(const f32x4*)sp, s1 = *(const f32x4*)(sp + 4);
    float x[16];
#pragma unroll
    for (int i = 0; i < 4; ++i) {
        x[2 * i]     = bf2f((u16)(p0[i] & 0xffff));
        x[2 * i + 1] = bf2f((u16)(p0[i] >> 16));
        x[8 + 2 * i]     = bf2f((u16)(p1[i] & 0xffff));
        x[8 + 2 * i + 1] = bf2f((u16)(p1[i] >> 16));
    }
    float c[8]  = {c0[0], c0[1], c0[2], c0[3], c1[0], c1[1], c1[2], c1[3]};
    float sn[8] = {s0[0], s0[1], s0[2], s0[3], s1[0], s1[1], s1[2], s1[3]};
    u32 ow[8];
#pragma unroll
    for (int i = 0; i < 8; ++i) {
        float xr = x[2 * i], xi = x[2 * i + 1];
        float orr = xr * c[i] - xi * sn[i];
        float oii = xr * sn[i] + xi * c[i];
        ow[i] = (u32)f2bf(orr) | ((u32)f2bf(oii) << 16);
    }
    u16* dst = (r ? kb : qb) + ((size_t)((b * 16 + h) * 2048 + s)) * 128 + e * 16;
    uint4v q0 = {ow[0], ow[1], ow[2], ow[3]};
    uint4v q1 = {ow[4], ow[5], ow[6], ow[7]};
    *(uint4v*)dst = q0;
    *(uint4v*)(dst + 8) = q1;
}

// ------------------------------------------------- causal flash attention
// qb/kb: [b][h][2048][128] bf16 (rope'd). V read from qkv buffer (col 4096+).
// Block: (qtile, h, b); 128 q rows; 4 waves x 32 rows. KVBLK=64.
__global__ __launch_bounds__(256, 2) void k_attn(const u16* __restrict__ qb,
                                                 const u16* __restrict__ kb,
                                                 const u16* __restrict__ qkv,
                                                 u16* __restrict__ yb) {
    __shared__ u16 Ks[64][128];   // swizzled 16B slots: slot ^= row&7
    __shared__ u16 Vt[128][64];   // V^T, swizzled 8B... stored as 16B slots: slot ^= ((row>>3)^row)&7
    __shared__ u16 Ps[4][32][72]; // per-wave P, padded
    const int qt = blockIdx.x, h = blockIdx.y, b = blockIdx.z;
    const int w = threadIdx.x >> 6, l = threadIdx.x & 63;
    const int lr = l & 15, lg = l >> 4;
    const int qw = qt * 128 + w * 32;

    const u16* qp = qb + (size_t)((b * 16 + h) * 2048) * 128;
    const u16* kp = kb + (size_t)((b * 16 + h) * 2048) * 128;
    const u16* vp = qkv + (size_t)(b * 2048) * 6144 + 4096 + h * 128;

    bf16x8 qf[2][4];
#pragma unroll
    for (int i = 0; i < 2; ++i)
#pragma unroll
        for (int ks = 0; ks < 4; ++ks)
            qf[i][ks] = *(const bf16x8*)(qp + (size_t)(qw + i * 16 + lr) * 128 + ks * 32 + lg * 8);

    f32x4 acc[2][8];
#pragma unroll
    for (int i = 0; i < 2; ++i)
#pragma unroll
        for (int j = 0; j < 8; ++j) acc[i][j] = (f32x4){0.f, 0.f, 0.f, 0.f};
    float mrow[2][4], lrow[2][4];
#pragma unroll
    for (int i = 0; i < 2; ++i)
#pragma unroll
        for (int r = 0; r < 4; ++r) { mrow[i][r] = -1e30f; lrow[i][r] = 0.f; }

    const float scale = 0.08838834764831845f;   // 1/sqrt(128)
    const int nkt = 2 * qt + 2;

    for (int kt = 0; kt < nkt; ++kt) {
        const int kbase = kt * 64;
        __syncthreads();   // prior-iter LDS reads done
        // ---- stage K tile (global_load_lds, source-swizzled)
        {
#pragma unroll
            for (int c = 0; c < 4; ++c) {
                const int row = w * 16 + c * 4 + lg;
                const int sslot = lr ^ (4 * (c & 1) + lg);
                const u16* g = kp + (size_t)(kbase + row) * 128 + sslot * 8;
                __builtin_amdgcn_global_load_lds(AS1(g), AS3(&Ks[w * 16 + c * 4][0]), 16, 0, 0);
            }
        }
        // ---- stage V tile transposed into Vt (reg-staged, swizzled)
        {
            const int rg = (int)threadIdx.x >> 4, cg = (int)threadIdx.x & 15;
            const u16* gv = vp + (size_t)(kbase + rg * 4) * 6144 + cg * 8;
            uint4v v0 = *(const uint4v*)gv;
            uint4v v1 = *(const uint4v*)(gv + 6144);
            uint4v v2 = *(const uint4v*)(gv + 2 * 6144);
            uint4v v3 = *(const uint4v*)(gv + 3 * 6144);
            const u16* u0 = (const u16*)&v0;
            const u16* u1 = (const u16*)&v1;
            const u16* u2 = (const u16*)&v2;
            const u16* u3 = (const u16*)&v3;
            const int sb = rg >> 1, hf = (rg & 1) * 4;
#pragma unroll
            for (int cc = 0; cc < 8; ++cc) {
                const int row = cg * 8 + cc;                       // hd index
                const int col = ((sb ^ ((cg ^ cc) & 7)) << 3) + hf; // swizzled sk pos
                ushort4v pk = {u0[cc], u1[cc], u2[cc], u3[cc]};
                *(ushort4v*)&Vt[row][col] = pk;
            }
        }
        __syncthreads();   // K (vmcnt) + Vt (lgkmcnt) visible

        if (kbase <= qw + 31) {
            // ---- S = Q K^T
            f32x4 sc[2][4];
#pragma unroll
            for (int i = 0; i < 2; ++i)
#pragma unroll
                for (int j = 0; j < 4; ++j) sc[i][j] = (f32x4){0.f, 0.f, 0.f, 0.f};
#pragma unroll
            for (int nt = 0; nt < 4; ++nt) {
#pragma unroll
                for (int ks = 0; ks < 4; ++ks) {
                    const int slot = (ks * 4 + lg) ^ (lr & 7);
                    bf16x8 kf = *(const bf16x8*)&Ks[nt * 16 + lr][slot * 8];
#pragma unroll
                    for (int mt = 0; mt < 2; ++mt)
                        sc[mt][nt] = __builtin_amdgcn_mfma_f32_16x16x32_bf16(qf[mt][ks], kf, sc[mt][nt], 0, 0, 0);
                }
            }
            // ---- scale + causal mask
            const bool pm = (kbase + 63 > qw);
#pragma unroll
            for (int mt = 0; mt < 2; ++mt)
#pragma unroll
                for (int nt = 0; nt < 4; ++nt)
#pragma unroll
                    for (int r = 0; r < 4; ++r) {
                        float v = sc[mt][nt][r] * scale;
                        if (pm) {
                            const int qi = qw + mt * 16 + lg * 4 + r;
                            const int ki = kbase + nt * 16 + lr;
                            if (ki > qi) v = -1e30f;
                        }
                        sc[mt][nt][r] = v;
                    }
            // ---- row max (reduce over 16 lanes of the lg-group)
            float rm[2][4];
#pragma unroll
            for (int mt = 0; mt < 2; ++mt)
#pragma unroll
                for (int r = 0; r < 4; ++r)
                    rm[mt][r] = fmaxf(fmaxf(sc[mt][0][r], sc[mt][1][r]),
                                      fmaxf(sc[mt][2][r], sc[mt][3][r]));
#pragma unroll
            for (int off = 8; off; off >>= 1)
#pragma unroll
                for (int mt = 0; mt < 2; ++mt)
#pragma unroll
                    for (int r = 0; r < 4; ++r)
                        rm[mt][r] = fmaxf(rm[mt][r], __shfl_xor(rm[mt][r], off, 16));
            // ---- online softmax update
            float fac[2][4];
#pragma unroll
            for (int mt = 0; mt < 2; ++mt)
#pragma unroll
                for (int r = 0; r < 4; ++r) {
                    const float mn = fmaxf(mrow[mt][r], rm[mt][r]);
                    fac[mt][r] = __expf(mrow[mt][r] - mn);
                    mrow[mt][r] = mn;
                    lrow[mt][r] *= fac[mt][r];
                }
#pragma unroll
            for (int mt = 0; mt < 2; ++mt)
#pragma unroll
                for (int nt = 0; nt < 8; ++nt)
#pragma unroll
                    for (int r = 0; r < 4; ++r) acc[mt][nt][r] *= fac[mt][r];
            float rs[2][4] = {{0.f, 0.f, 0.f, 0.f}, {0.f, 0.f, 0.f, 0.f}};
#pragma unroll
            for (int mt = 0; mt < 2; ++mt)
#pragma unroll
                for (int nt = 0; nt < 4; ++nt)
#pragma unroll
                    for (int r = 0; r < 4; ++r) {
                        const float p = __expf(sc[mt][nt][r] - mrow[mt][r]);
                        sc[mt][nt][r] = p;
                        rs[mt][r] += p;
                    }
#pragma unroll
            for (int off = 8; off; off >>= 1)
#pragma unroll
                for (int mt = 0; mt < 2; ++mt)
#pragma unroll
                    for (int r = 0; r < 4; ++r)
                        rs[mt][r] += __shfl_xor(rs[mt][r], off, 16);
#pragma unroll
            for (int mt = 0; mt < 2; ++mt)
#pragma unroll
                for (int r = 0; r < 4; ++r) lrow[mt][r] += rs[mt][r];
            // ---- P -> LDS (bf16, per-wave region)
#pragma unroll
            for (int mt = 0; mt < 2; ++mt)
#pragma unroll
                for (int nt = 0; nt < 4; ++nt)
#pragma unroll
                    for (int r = 0; r < 4; ++r)
                        Ps[w][mt * 16 + lg * 4 + r][nt * 16 + lr] = f2bf(sc[mt][nt][r]);
            // ---- PV
#pragma unroll
            for (int k2 = 0; k2 < 2; ++k2) {
                bf16x8 pa[2];
                pa[0] = *(const bf16x8*)&Ps[w][lr][k2 * 32 + lg * 8];
                pa[1] = *(const bf16x8*)&Ps[w][16 + lr][k2 * 32 + lg * 8];
#pragma unroll
                for (int nt = 0; nt < 8; ++nt) {
                    const int f = ((nt * 2 + (lr >> 3)) ^ lr) & 7;
                    const int slot = (k2 * 4 + lg) ^ f;
                    bf16x8 vb = *(const bf16x8*)&Vt[nt * 16 + lr][slot * 8];
#pragma unroll
                    for (int mt = 0; mt < 2; ++mt)
                        acc[mt][nt] = __builtin_amdgcn_mfma_f32_16x16x32_bf16(pa[mt], vb, acc[mt][nt], 0, 0, 0);
                }
            }
        }
    }

    // ---- epilogue: y = acc / l, write [b][s][h*128+..] bf16
    u16* yp = yb + (size_t)(b * 2048) * 2048 + h * 128;
#pragma unroll
    for (int mt = 0; mt < 2; ++mt)
#pragma unroll
        for (int r = 0; r < 4; ++r) {
            const float inv = 1.f / lrow[mt][r];
            const size_t row = qw + mt * 16 + lg * 4 + r;
#pragma unroll
            for (int nt = 0; nt < 8; ++nt)
                yp[row * 2048 + nt * 16 + lr] = f2bf(acc[mt][nt][r] * inv);
        }
}

// --------------------------------------------------------------------------
extern "C" void kernel_launch(void* const* d_in, const int* in_sizes, int n_in,
                              void* d_out, int out_size, void* d_ws, size_t ws_size,
                              hipStream_t stream) {
    const float* x    = (const float*)d_in[0];
    const float* fcos = (const float*)d_in[1];
    const float* fsin = (const float*)d_in[2];
    const float* Wqkv = (const float*)d_in[3];
    const float* bqkv = (const float*)d_in[4];
    const float* Wout = (const float*)d_in[5];
    const float* bout = (const float*)d_in[6];
    float* out = (float*)d_out;

    if (ws_size < 234881024u) return;   // need 224 MB scratch

    char* ws = (char*)d_ws;
    u16* x_bf  = (u16*)(ws);                 // 32 MB  (aliased later by yb)
    u16* wqkvT = (u16*)(ws + 33554432);      // 24 MB
    u16* woutT = (u16*)(ws + 58720256);      //  8 MB
    u16* qkv   = (u16*)(ws + 67108864);      // 96 MB (q,k,v bf16; v read in-place)
    u16* qb    = (u16*)(ws + 167772160);     // 32 MB
    u16* kb    = (u16*)(ws + 201326592);     // 32 MB
    u16* yb    = x_bf;                       // alias: x_bf dead after GEMM1

    k_cvt_bf16<<<8192, 256, 0, stream>>>(x, x_bf, 2097152);
    k_transpose_bf16<<<dim3(192, 64), 256, 0, stream>>>(Wqkv, wqkvT, 2048, 6144);
    k_transpose_bf16<<<dim3(64, 64), 256, 0, stream>>>(Wout, woutT, 2048, 2048);
    k_gemm_bt<1><<<dim3(64, 48), 256, 0, stream>>>(x_bf, wqkvT, bqkv, qkv, 8192, 6144, 2048);
    k_rope<<<8192, 256, 0, stream>>>(qkv, fcos, fsin, qb, kb);
    k_attn<<<dim3(16, 16, 4), 256, 0, stream>>>(qb, kb, qkv, yb);
    k_gemm_bt<0><<<dim3(64, 16), 256, 0, stream>>>(yb, woutT, bout, out, 8192, 2048, 2048);
}

// Round 4
// 709.476 us; speedup vs baseline: 1.0009x; 1.0009x over previous
//
#include <hip/hip_runtime.h>

typedef __attribute__((ext_vector_type(4))) float f32x4;
typedef __attribute__((ext_vector_type(8))) short bf16x8;
typedef __attribute__((ext_vector_type(4))) unsigned int uint4v;
typedef __attribute__((ext_vector_type(4))) unsigned short ushort4v;
typedef unsigned short u16;
typedef unsigned int u32;

#define AS1(p) ((const __attribute__((address_space(1))) u32*)(p))
#define AS3(p) ((__attribute__((address_space(3))) u32*)(p))

__device__ __forceinline__ float bf2f(u16 v) {
    u32 u = ((u32)v) << 16;
    return __builtin_bit_cast(float, u);
}
__device__ __forceinline__ u16 f2bf(float f) {
    u32 u = __builtin_bit_cast(u32, f);
    u += 0x7fffu + ((u >> 16) & 1u);   // RNE
    return (u16)(u >> 16);
}

// ---------------------------------------------------------------- convert x
__global__ __launch_bounds__(256) void k_cvt_bf16(const float* __restrict__ in,
                                                  u16* __restrict__ out, int n8) {
    int t = blockIdx.x * 256 + threadIdx.x;
    if (t >= n8) return;
    const f32x4* p = (const f32x4*)in + (size_t)t * 2;
    f32x4 a = p[0], b = p[1];
    uint4v o;
    o[0] = (u32)f2bf(a[0]) | ((u32)f2bf(a[1]) << 16);
    o[1] = (u32)f2bf(a[2]) | ((u32)f2bf(a[3]) << 16);
    o[2] = (u32)f2bf(b[0]) | ((u32)f2bf(b[1]) << 16);
    o[3] = (u32)f2bf(b[2]) | ((u32)f2bf(b[3]) << 16);
    *((uint4v*)(out + (size_t)t * 8)) = o;
}

// ------------------------------------------- transpose-convert W -> W^T bf16
__global__ __launch_bounds__(256) void k_transpose_bf16(const float* __restrict__ in,
                                                        u16* __restrict__ out,
                                                        int R, int C) {
    __shared__ float tile[32][33];
    const int bx = blockIdx.x * 32, by = blockIdx.y * 32;
    const int tx = threadIdx.x & 31, ty = threadIdx.x >> 5;   // 256 threads
#pragma unroll
    for (int i = 0; i < 32; i += 8)
        tile[ty + i][tx] = in[(size_t)(by + ty + i) * C + bx + tx];
    __syncthreads();
#pragma unroll
    for (int i = 0; i < 32; i += 8)
        out[(size_t)(bx + ty + i) * R + by + tx] = f2bf(tile[tx][ty + i]);
}

// ----------------------------------------------------- GEMM  C = A * B^T + b
// A: [M][K] bf16, Bt: [N][K] bf16, bias[N] f32. 128x128 tile, BK=32, 4 waves.
template <int OUT_BF16>
__global__ __launch_bounds__(256) void k_gemm_bt(const u16* __restrict__ A,
                                                 const u16* __restrict__ Bt,
                                                 const float* __restrict__ bias,
                                                 void* __restrict__ Cout,
                                                 int M, int N, int K) {
    __shared__ u16 As[128][32];
    __shared__ u16 Bs[128][32];
    const int w = threadIdx.x >> 6, l = threadIdx.x & 63;
    const int lr = l & 15, lg = l >> 4;
    const size_t brow = (size_t)blockIdx.x * 128, bcol = (size_t)blockIdx.y * 128;
    const int wm = (w >> 1) * 64, wn = (w & 1) * 64;

    f32x4 acc[4][4];
#pragma unroll
    for (int i = 0; i < 4; ++i)
#pragma unroll
        for (int j = 0; j < 4; ++j) acc[i][j] = (f32x4){0.f, 0.f, 0.f, 0.f};

    // staging: chunks 2w,2w+1 of 16 rows each; XOR slot swizzle on source
    const int srow = w * 32 + (l >> 2);
    const int scol = ((l & 3) ^ ((l >> 3) & 3)) * 8;
    const u16* ga = A + ((size_t)brow + srow) * K + scol;
    const u16* gb = Bt + ((size_t)bcol + srow) * K + scol;
    u16* lA = &As[w * 32][0];
    u16* lB = &Bs[w * 32][0];
    const int rslot = (lg ^ ((lr >> 1) & 3)) * 8;   // swizzled read slot

    for (int k0 = 0; k0 < K; k0 += 32) {
        __syncthreads();
        __builtin_amdgcn_global_load_lds(AS1(ga + k0), AS3(lA), 16, 0, 0);
        __builtin_amdgcn_global_load_lds(AS1(ga + (size_t)16 * K + k0), AS3(lA + 512), 16, 0, 0);
        __builtin_amdgcn_global_load_lds(AS1(gb + k0), AS3(lB), 16, 0, 0);
        __builtin_amdgcn_global_load_lds(AS1(gb + (size_t)16 * K + k0), AS3(lB + 512), 16, 0, 0);
        __syncthreads();
        bf16x8 af[4], bff[4];
#pragma unroll
        for (int i = 0; i < 4; ++i) {
            af[i]  = *(const bf16x8*)&As[wm + i * 16 + lr][rslot];
            bff[i] = *(const bf16x8*)&Bs[wn + i * 16 + lr][rslot];
        }
#pragma unroll
        for (int i = 0; i < 4; ++i)
#pragma unroll
            for (int j = 0; j < 4; ++j)
                acc[i][j] = __builtin_amdgcn_mfma_f32_16x16x32_bf16(af[i], bff[j], acc[i][j], 0, 0, 0);
    }

#pragma unroll
    for (int i = 0; i < 4; ++i) {
        const size_t row0 = brow + wm + i * 16 + lg * 4;
#pragma unroll
        for (int j = 0; j < 4; ++j) {
            const size_t col = bcol + wn + j * 16 + lr;
            const float bv = bias[col];
#pragma unroll
            for (int r = 0; r < 4; ++r) {
                float v = acc[i][j][r] + bv;
                if (OUT_BF16)
                    ((u16*)Cout)[(row0 + r) * N + col] = f2bf(v);
                else
                    ((float*)Cout)[(row0 + r) * N + col] = v;
            }
        }
    }
}

// ------------------------------------------------------------------- RoPE
// qkv[b][s][6144] bf16 -> qb/kb [b][h][s][128] bf16 (rope applied)
__global__ __launch_bounds__(256) void k_rope(const u16* __restrict__ qkv,
                                              const float* __restrict__ fcos,
                                              const float* __restrict__ fsin,
                                              u16* __restrict__ qb, u16* __restrict__ kb) {
    const int t = blockIdx.x * 256 + threadIdx.x;
    const int e = t & 7, h = (t >> 3) & 15, r = (t >> 7) & 1, s = (t >> 8) & 2047, b = t >> 19;
    const u16* src = qkv + ((size_t)(b * 2048 + s)) * 6144 + r * 2048 + h * 128 + e * 16;
    uint4v p0 = *(const uint4v*)src;
    uint4v p1 = *(const uint4v*)(src + 8);
    const float* cp = fcos + s * 64 + e * 8;
    const float* sp = fsin + s * 64 + e * 8;
    f32x4 c0 = *(const f32x4*)cp, c1 = *(const f32x4*)(cp + 4);
    f32x4 s0 = *(const f32x4*)sp, s1 = *(const f32x4*)(sp + 4);
    float x[16];
#pragma unroll
    for (int i = 0; i < 4; ++i) {
        x[2 * i]     = bf2f((u16)(p0[i] & 0xffff));
        x[2 * i + 1] = bf2f((u16)(p0[i] >> 16));
        x[8 + 2 * i]     = bf2f((u16)(p1[i] & 0xffff));
        x[8 + 2 * i + 1] = bf2f((u16)(p1[i] >> 16));
    }
    float c[8]  = {c0[0], c0[1], c0[2], c0[3], c1[0], c1[1], c1[2], c1[3]};
    float sn[8] = {s0[0], s0[1], s0[2], s0[3], s1[0], s1[1], s1[2], s1[3]};
    u32 ow[8];
#pragma unroll
    for (int i = 0; i < 8; ++i) {
        float xr = x[2 * i], xi = x[2 * i + 1];
        float orr = xr * c[i] - xi * sn[i];
        float oii = xr * sn[i] + xi * c[i];
        ow[i] = (u32)f2bf(orr) | ((u32)f2bf(oii) << 16);
    }
    u16* dst = (r ? kb : qb) + ((size_t)((b * 16 + h) * 2048 + s)) * 128 + e * 16;
    uint4v q0 = {ow[0], ow[1], ow[2], ow[3]};
    uint4v q1 = {ow[4], ow[5], ow[6], ow[7]};
    *(uint4v*)dst = q0;
    *(uint4v*)(dst + 8) = q1;
}

// ------------------------------------------------- causal flash attention
// qb/kb: [b][h][2048][128] bf16 (rope'd). V read from qkv buffer (col 4096+).
// Block: (qtile, h, b); 128 q rows; 4 waves x 32 rows. KVBLK=64.
__global__ __launch_bounds__(256, 2) void k_attn(const u16* __restrict__ qb,
                                                 const u16* __restrict__ kb,
                                                 const u16* __restrict__ qkv,
                                                 u16* __restrict__ yb) {
    __shared__ u16 Ks[64][128];   // swizzled 16B slots: slot ^= row&7
    __shared__ u16 Vt[128][64];   // V^T, swizzled 8B... stored as 16B slots: slot ^= ((row>>3)^row)&7
    __shared__ u16 Ps[4][32][72]; // per-wave P, padded
    const int qt = blockIdx.x, h = blockIdx.y, b = blockIdx.z;
    const int w = threadIdx.x >> 6, l = threadIdx.x & 63;
    const int lr = l & 15, lg = l >> 4;
    const int qw = qt * 128 + w * 32;

    const u16* qp = qb + (size_t)((b * 16 + h) * 2048) * 128;
    const u16* kp = kb + (size_t)((b * 16 + h) * 2048) * 128;
    const u16* vp = qkv + (size_t)(b * 2048) * 6144 + 4096 + h * 128;

    bf16x8 qf[2][4];
#pragma unroll
    for (int i = 0; i < 2; ++i)
#pragma unroll
        for (int ks = 0; ks < 4; ++ks)
            qf[i][ks] = *(const bf16x8*)(qp + (size_t)(qw + i * 16 + lr) * 128 + ks * 32 + lg * 8);

    f32x4 acc[2][8];
#pragma unroll
    for (int i = 0; i < 2; ++i)
#pragma unroll
        for (int j = 0; j < 8; ++j) acc[i][j] = (f32x4){0.f, 0.f, 0.f, 0.f};
    float mrow[2][4], lrow[2][4];
#pragma unroll
    for (int i = 0; i < 2; ++i)
#pragma unroll
        for (int r = 0; r < 4; ++r) { mrow[i][r] = -1e30f; lrow[i][r] = 0.f; }

    const float scale = 0.08838834764831845f;   // 1/sqrt(128)
    const int nkt = 2 * qt + 2;

    for (int kt = 0; kt < nkt; ++kt) {
        const int kbase = kt * 64;
        __syncthreads();   // prior-iter LDS reads done
        // ---- stage K tile (global_load_lds, source-swizzled)
        {
#pragma unroll
            for (int c = 0; c < 4; ++c) {
                const int row = w * 16 + c * 4 + lg;
                const int sslot = lr ^ (4 * (c & 1) + lg);
                const u16* g = kp + (size_t)(kbase + row) * 128 + sslot * 8;
                __builtin_amdgcn_global_load_lds(AS1(g), AS3(&Ks[w * 16 + c * 4][0]), 16, 0, 0);
            }
        }
        // ---- stage V tile transposed into Vt (reg-staged, swizzled)
        {
            const int rg = (int)threadIdx.x >> 4, cg = (int)threadIdx.x & 15;
            const u16* gv = vp + (size_t)(kbase + rg * 4) * 6144 + cg * 8;
            uint4v v0 = *(const uint4v*)gv;
            uint4v v1 = *(const uint4v*)(gv + 6144);
            uint4v v2 = *(const uint4v*)(gv + 2 * 6144);
            uint4v v3 = *(const uint4v*)(gv + 3 * 6144);
            const u16* u0 = (const u16*)&v0;
            const u16* u1 = (const u16*)&v1;
            const u16* u2 = (const u16*)&v2;
            const u16* u3 = (const u16*)&v3;
            const int sb = rg >> 1, hf = (rg & 1) * 4;
#pragma unroll
            for (int cc = 0; cc < 8; ++cc) {
                const int row = cg * 8 + cc;                       // hd index
                const int col = ((sb ^ ((cg ^ cc) & 7)) << 3) + hf; // swizzled sk pos
                ushort4v pk = {u0[cc], u1[cc], u2[cc], u3[cc]};
                *(ushort4v*)&Vt[row][col] = pk;
            }
        }
        __syncthreads();   // K (vmcnt) + Vt (lgkmcnt) visible

        if (kbase <= qw + 31) {
            // ---- S = Q K^T
            f32x4 sc[2][4];
#pragma unroll
            for (int i = 0; i < 2; ++i)
#pragma unroll
                for (int j = 0; j < 4; ++j) sc[i][j] = (f32x4){0.f, 0.f, 0.f, 0.f};
#pragma unroll
            for (int nt = 0; nt < 4; ++nt) {
#pragma unroll
                for (int ks = 0; ks < 4; ++ks) {
                    const int slot = (ks * 4 + lg) ^ (lr & 7);
                    bf16x8 kf = *(const bf16x8*)&Ks[nt * 16 + lr][slot * 8];
#pragma unroll
                    for (int mt = 0; mt < 2; ++mt)
                        sc[mt][nt] = __builtin_amdgcn_mfma_f32_16x16x32_bf16(qf[mt][ks], kf, sc[mt][nt], 0, 0, 0);
                }
            }
            // ---- scale + causal mask
            const bool pm = (kbase + 63 > qw);
#pragma unroll
            for (int mt = 0; mt < 2; ++mt)
#pragma unroll
                for (int nt = 0; nt < 4; ++nt)
#pragma unroll
                    for (int r = 0; r < 4; ++r) {
                        float v = sc[mt][nt][r] * scale;
                        if (pm) {
                            const int qi = qw + mt * 16 + lg * 4 + r;
                            const int ki = kbase + nt * 16 + lr;
                            if (ki > qi) v = -1e30f;
                        }
                        sc[mt][nt][r] = v;
                    }
            // ---- row max (reduce over 16 lanes of the lg-group)
            float rm[2][4];
#pragma unroll
            for (int mt = 0; mt < 2; ++mt)
#pragma unroll
                for (int r = 0; r < 4; ++r)
                    rm[mt][r] = fmaxf(fmaxf(sc[mt][0][r], sc[mt][1][r]),
                                      fmaxf(sc[mt][2][r], sc[mt][3][r]));
#pragma unroll
            for (int off = 8; off; off >>= 1)
#pragma unroll
                for (int mt = 0; mt < 2; ++mt)
#pragma unroll
                    for (int r = 0; r < 4; ++r)
                        rm[mt][r] = fmaxf(rm[mt][r], __shfl_xor(rm[mt][r], off, 16));
            // ---- online softmax update
            float fac[2][4];
#pragma unroll
            for (int mt = 0; mt < 2; ++mt)
#pragma unroll
                for (int r = 0; r < 4; ++r) {
                    const float mn = fmaxf(mrow[mt][r], rm[mt][r]);
                    fac[mt][r] = __expf(mrow[mt][r] - mn);
                    mrow[mt][r] = mn;
                    lrow[mt][r] *= fac[mt][r];
                }
#pragma unroll
            for (int mt = 0; mt < 2; ++mt)
#pragma unroll
                for (int nt = 0; nt < 8; ++nt)
#pragma unroll
                    for (int r = 0; r < 4; ++r) acc[mt][nt][r] *= fac[mt][r];
            float rs[2][4] = {{0.f, 0.f, 0.f, 0.f}, {0.f, 0.f, 0.f, 0.f}};
#pragma unroll
            for (int mt = 0; mt < 2; ++mt)
#pragma unroll
                for (int nt = 0; nt < 4; ++nt)
#pragma unroll
                    for (int r = 0; r < 4; ++r) {
                        const float p = __expf(sc[mt][nt][r] - mrow[mt][r]);
                        sc[mt][nt][r] = p;
                        rs[mt][r] += p;
                    }
#pragma unroll
            for (int off = 8; off; off >>= 1)
#pragma unroll
                for (int mt = 0; mt < 2; ++mt)
#pragma unroll
                    for (int r = 0; r < 4; ++r)
                        rs[mt][r] += __shfl_xor(rs[mt][r], off, 16);
#pragma unroll
            for (int mt = 0; mt < 2; ++mt)
#pragma unroll
                for (int r = 0; r < 4; ++r) lrow[mt][r] += rs[mt][r];
            // ---- P -> LDS (bf16, per-wave region)
#pragma unroll
            for (int mt = 0; mt < 2; ++mt)
#pragma unroll
                for (int nt = 0; nt < 4; ++nt)
#pragma unroll
                    for (int r = 0; r < 4; ++r)
                        Ps[w][mt * 16 + lg * 4 + r][nt * 16 + lr] = f2bf(sc[mt][nt][r]);
            // ---- PV
#pragma unroll
            for (int k2 = 0; k2 < 2; ++k2) {
                bf16x8 pa[2];
                pa[0] = *(const bf16x8*)&Ps[w][lr][k2 * 32 + lg * 8];
                pa[1] = *(const bf16x8*)&Ps[w][16 + lr][k2 * 32 + lg * 8];
#pragma unroll
                for (int nt = 0; nt < 8; ++nt) {
                    const int f = ((nt * 2 + (lr >> 3)) ^ lr) & 7;
                    const int slot = (k2 * 4 + lg) ^ f;
                    bf16x8 vb = *(const bf16x8*)&Vt[nt * 16 + lr][slot * 8];
#pragma unroll
                    for (int mt = 0; mt < 2; ++mt)
                        acc[mt][nt] = __builtin_amdgcn_mfma_f32_16x16x32_bf16(pa[mt], vb, acc[mt][nt], 0, 0, 0);
                }
            }
        }
    }

    // ---- epilogue: y = acc / l, write [b][s][h*128+..] bf16
    u16* yp = yb + (size_t)(b * 2048) * 2048 + h * 128;
#pragma unroll
    for (int mt = 0; mt < 2; ++mt)
#pragma unroll
        for (int r = 0; r < 4; ++r) {
            const float inv = 1.f / lrow[mt][r];
            const size_t row = qw + mt * 16 + lg * 4 + r;
#pragma unroll
            for (int nt = 0; nt < 8; ++nt)
                yp[row * 2048 + nt * 16 + lr] = f2bf(acc[mt][nt][r] * inv);
        }
}

// --------------------------------------------------------------------------
extern "C" void kernel_launch(void* const* d_in, const int* in_sizes, int n_in,
                              void* d_out, int out_size, void* d_ws, size_t ws_size,
                              hipStream_t stream) {
    const float* x    = (const float*)d_in[0];
    const float* fcos = (const float*)d_in[1];
    const float* fsin = (const float*)d_in[2];
    const float* Wqkv = (const float*)d_in[3];
    const float* bqkv = (const float*)d_in[4];
    const float* Wout = (const float*)d_in[5];
    const float* bout = (const float*)d_in[6];
    float* out = (float*)d_out;

    if (ws_size < 234881024u) return;   // need 224 MB scratch

    char* ws = (char*)d_ws;
    u16* x_bf  = (u16*)(ws);                 // 32 MB  (aliased later by yb)
    u16* wqkvT = (u16*)(ws + 33554432);      // 24 MB
    u16* woutT = (u16*)(ws + 58720256);      //  8 MB
    u16* qkv   = (u16*)(ws + 67108864);      // 96 MB (q,k,v bf16; v read in-place)
    u16* qb    = (u16*)(ws + 167772160);     // 32 MB
    u16* kb    = (u16*)(ws + 201326592);     // 32 MB
    u16* yb    = x_bf;                       // alias: x_bf dead after GEMM1

    k_cvt_bf16<<<8192, 256, 0, stream>>>(x, x_bf, 2097152);
    k_transpose_bf16<<<dim3(192, 64), 256, 0, stream>>>(Wqkv, wqkvT, 2048, 6144);
    k_transpose_bf16<<<dim3(64, 64), 256, 0, stream>>>(Wout, woutT, 2048, 2048);
    k_gemm_bt<1><<<dim3(64, 48), 256, 0, stream>>>(x_bf, wqkvT, bqkv, qkv, 8192, 6144, 2048);
    k_rope<<<8192, 256, 0, stream>>>(qkv, fcos, fsin, qb, kb);
    k_attn<<<dim3(16, 16, 4), 256, 0, stream>>>(qb, kb, qkv, yb);
    k_gemm_bt<0><<<dim3(64, 16), 256, 0, stream>>>(yb, woutT, bout, out, 8192, 2048, 2048);
}

// Round 5
// 649.433 us; speedup vs baseline: 1.0935x; 1.0925x over previous
//
#include <hip/hip_runtime.h>

typedef __attribute__((ext_vector_type(4))) float f32x4;
typedef __attribute__((ext_vector_type(8))) short bf16x8;
typedef __attribute__((ext_vector_type(4))) unsigned int uint4v;
typedef __attribute__((ext_vector_type(4))) unsigned short ushort4v;
typedef unsigned short u16;
typedef unsigned int u32;

#define AS1(p) ((const __attribute__((address_space(1))) u32*)(p))
#define AS3(p) ((__attribute__((address_space(3))) u32*)(p))

__device__ __forceinline__ float bf2f(u16 v) {
    u32 u = ((u32)v) << 16;
    return __builtin_bit_cast(float, u);
}
__device__ __forceinline__ u16 f2bf(float f) {
    u32 u = __builtin_bit_cast(u32, f);
    u += 0x7fffu + ((u >> 16) & 1u);   // RNE
    return (u16)(u >> 16);
}

// ---------------------------------------------------------------- convert x
__global__ __launch_bounds__(256) void k_cvt_bf16(const float* __restrict__ in,
                                                  u16* __restrict__ out, int n8) {
    int t = blockIdx.x * 256 + threadIdx.x;
    if (t >= n8) return;
    const f32x4* p = (const f32x4*)in + (size_t)t * 2;
    f32x4 a = p[0], b = p[1];
    uint4v o;
    o[0] = (u32)f2bf(a[0]) | ((u32)f2bf(a[1]) << 16);
    o[1] = (u32)f2bf(a[2]) | ((u32)f2bf(a[3]) << 16);
    o[2] = (u32)f2bf(b[0]) | ((u32)f2bf(b[1]) << 16);
    o[3] = (u32)f2bf(b[2]) | ((u32)f2bf(b[3]) << 16);
    *((uint4v*)(out + (size_t)t * 8)) = o;
}

// ------------------------------------------- transpose-convert W -> W^T bf16
__global__ __launch_bounds__(256) void k_transpose_bf16(const float* __restrict__ in,
                                                        u16* __restrict__ out,
                                                        int R, int C) {
    __shared__ float tile[32][33];
    const int bx = blockIdx.x * 32, by = blockIdx.y * 32;
    const int tx = threadIdx.x & 31, ty = threadIdx.x >> 5;   // 256 threads
#pragma unroll
    for (int i = 0; i < 32; i += 8)
        tile[ty + i][tx] = in[(size_t)(by + ty + i) * C + bx + tx];
    __syncthreads();
#pragma unroll
    for (int i = 0; i < 32; i += 8)
        out[(size_t)(bx + ty + i) * R + by + tx] = f2bf(tile[tx][ty + i]);
}

// ----------------------------------------------------- GEMM  C = A * B^T + b
// A: [M][K] bf16, Bt: [N][K] bf16, bias[N] f32. 128x128 tile, BK=32, 4 waves.
template <int OUT_BF16>
__global__ __launch_bounds__(256) void k_gemm_bt(const u16* __restrict__ A,
                                                 const u16* __restrict__ Bt,
                                                 const float* __restrict__ bias,
                                                 void* __restrict__ Cout,
                                                 int M, int N, int K) {
    __shared__ u16 As[128][32];
    __shared__ u16 Bs[128][32];
    const int w = threadIdx.x >> 6, l = threadIdx.x & 63;
    const int lr = l & 15, lg = l >> 4;
    const size_t brow = (size_t)blockIdx.x * 128, bcol = (size_t)blockIdx.y * 128;
    const int wm = (w >> 1) * 64, wn = (w & 1) * 64;

    f32x4 acc[4][4];
#pragma unroll
    for (int i = 0; i < 4; ++i)
#pragma unroll
        for (int j = 0; j < 4; ++j) acc[i][j] = (f32x4){0.f, 0.f, 0.f, 0.f};

    // staging: chunks 2w,2w+1 of 16 rows each; XOR slot swizzle on source
    const int srow = w * 32 + (l >> 2);
    const int scol = ((l & 3) ^ ((l >> 3) & 3)) * 8;
    const u16* ga = A + ((size_t)brow + srow) * K + scol;
    const u16* gb = Bt + ((size_t)bcol + srow) * K + scol;
    u16* lA = &As[w * 32][0];
    u16* lB = &Bs[w * 32][0];
    const int rslot = (lg ^ ((lr >> 1) & 3)) * 8;   // swizzled read slot

    for (int k0 = 0; k0 < K; k0 += 32) {
        __syncthreads();
        __builtin_amdgcn_global_load_lds(AS1(ga + k0), AS3(lA), 16, 0, 0);
        __builtin_amdgcn_global_load_lds(AS1(ga + (size_t)16 * K + k0), AS3(lA + 512), 16, 0, 0);
        __builtin_amdgcn_global_load_lds(AS1(gb + k0), AS3(lB), 16, 0, 0);
        __builtin_amdgcn_global_load_lds(AS1(gb + (size_t)16 * K + k0), AS3(lB + 512), 16, 0, 0);
        __syncthreads();
        bf16x8 af[4], bff[4];
#pragma unroll
        for (int i = 0; i < 4; ++i) {
            af[i]  = *(const bf16x8*)&As[wm + i * 16 + lr][rslot];
            bff[i] = *(const bf16x8*)&Bs[wn + i * 16 + lr][rslot];
        }
#pragma unroll
        for (int i = 0; i < 4; ++i)
#pragma unroll
            for (int j = 0; j < 4; ++j)
                acc[i][j] = __builtin_amdgcn_mfma_f32_16x16x32_bf16(af[i], bff[j], acc[i][j], 0, 0, 0);
    }

#pragma unroll
    for (int i = 0; i < 4; ++i) {
        const size_t row0 = brow + wm + i * 16 + lg * 4;
#pragma unroll
        for (int j = 0; j < 4; ++j) {
            const size_t col = bcol + wn + j * 16 + lr;
            const float bv = bias[col];
#pragma unroll
            for (int r = 0; r < 4; ++r) {
                float v = acc[i][j][r] + bv;
                if (OUT_BF16)
                    ((u16*)Cout)[(row0 + r) * N + col] = f2bf(v);
                else
                    ((float*)Cout)[(row0 + r) * N + col] = v;
            }
        }
    }
}

// ------------------------------------------------------------------- RoPE
// qkv[b][s][6144] bf16 -> qb/kb [b][h][s][128] bf16 (rope applied)
__global__ __launch_bounds__(256) void k_rope(const u16* __restrict__ qkv,
                                              const float* __restrict__ fcos,
                                              const float* __restrict__ fsin,
                                              u16* __restrict__ qb, u16* __restrict__ kb) {
    const int t = blockIdx.x * 256 + threadIdx.x;
    const int e = t & 7, h = (t >> 3) & 15, r = (t >> 7) & 1, s = (t >> 8) & 2047, b = t >> 19;
    const u16* src = qkv + ((size_t)(b * 2048 + s)) * 6144 + r * 2048 + h * 128 + e * 16;
    uint4v p0 = *(const uint4v*)src;
    uint4v p1 = *(const uint4v*)(src + 8);
    const float* cp = fcos + s * 64 + e * 8;
    const float* sp = fsin + s * 64 + e * 8;
    f32x4 c0 = *(const f32x4*)cp, c1 = *(const f32x4*)(cp + 4);
    f32x4 s0 = *(const f32x4*)sp, s1 = *(const f32x4*)(sp + 4);
    float x[16];
#pragma unroll
    for (int i = 0; i < 4; ++i) {
        x[2 * i]     = bf2f((u16)(p0[i] & 0xffff));
        x[2 * i + 1] = bf2f((u16)(p0[i] >> 16));
        x[8 + 2 * i]     = bf2f((u16)(p1[i] & 0xffff));
        x[8 + 2 * i + 1] = bf2f((u16)(p1[i] >> 16));
    }
    float c[8]  = {c0[0], c0[1], c0[2], c0[3], c1[0], c1[1], c1[2], c1[3]};
    float sn[8] = {s0[0], s0[1], s0[2], s0[3], s1[0], s1[1], s1[2], s1[3]};
    u32 ow[8];
#pragma unroll
    for (int i = 0; i < 8; ++i) {
        float xr = x[2 * i], xi = x[2 * i + 1];
        float orr = xr * c[i] - xi * sn[i];
        float oii = xr * sn[i] + xi * c[i];
        ow[i] = (u32)f2bf(orr) | ((u32)f2bf(oii) << 16);
    }
    u16* dst = (r ? kb : qb) + ((size_t)((b * 16 + h) * 2048 + s)) * 128 + e * 16;
    uint4v q0 = {ow[0], ow[1], ow[2], ow[3]};
    uint4v q1 = {ow[4], ow[5], ow[6], ow[7]};
    *(uint4v*)dst = q0;
    *(uint4v*)(dst + 8) = q1;
}

// ------------------------------------------------- causal flash attention
// Pipelined: double-buffered K (global_load_lds), reg-split V staging (T14),
// paired q-tiles (x, 15-x) per block for uniform 34-iteration blocks,
// XCD-locality block mapping (id%8 == (b*16+h)%8).
struct VtRegs { uint4v v0, v1, v2, v3; };

__device__ __forceinline__ void attn_stage_k(const u16* kp, int kbase, u16* dstBase,
                                             int w, int lr, int lg) {
#pragma unroll
    for (int c = 0; c < 4; ++c) {
        const int row = w * 16 + c * 4 + lg;
        const int sslot = lr ^ (4 * (c & 1) + lg);           // inverse swizzle on source
        const u16* gsrc = kp + (size_t)(kbase + row) * 128 + sslot * 8;
        __builtin_amdgcn_global_load_lds(AS1(gsrc), AS3(dstBase + (w * 16 + c * 4) * 128), 16, 0, 0);
    }
}

__device__ __forceinline__ VtRegs attn_load_v(const u16* vp, int kbase, int tid) {
    const int rg = tid >> 4, cg = tid & 15;
    const u16* gv = vp + (size_t)(kbase + rg * 4) * 6144 + cg * 8;
    VtRegs r;
    r.v0 = *(const uint4v*)gv;
    r.v1 = *(const uint4v*)(gv + 6144);
    r.v2 = *(const uint4v*)(gv + 2 * 6144);
    r.v3 = *(const uint4v*)(gv + 3 * 6144);
    return r;
}

__device__ __forceinline__ void attn_write_v(u16 (*Vt)[64], const VtRegs& r, int tid) {
    const int rg = tid >> 4, cg = tid & 15;
    const u16* u0 = (const u16*)&r.v0;
    const u16* u1 = (const u16*)&r.v1;
    const u16* u2 = (const u16*)&r.v2;
    const u16* u3 = (const u16*)&r.v3;
    const int sb = rg >> 1, hf = (rg & 1) * 4;
#pragma unroll
    for (int cc = 0; cc < 8; ++cc) {
        const int row = cg * 8 + cc;                          // hd index
        const int col = ((sb ^ ((cg ^ cc) & 7)) << 3) + hf;   // swizzled seq slot
        ushort4v pk = {u0[cc], u1[cc], u2[cc], u3[cc]};
        *(ushort4v*)&Vt[row][col] = pk;
    }
}

__device__ __forceinline__ void attn_qtile(int qt, const u16* qp, const u16* kp,
                                           const u16* vp, u16* yp,
                                           u16 (*Ks)[64][128], u16 (*Vt)[64],
                                           u16 (*Psw)[72],
                                           int w, int lr, int lg, int tid) {
    const int qw = qt * 128 + w * 32;

    bf16x8 qf[2][4];
#pragma unroll
    for (int i = 0; i < 2; ++i)
#pragma unroll
        for (int ks = 0; ks < 4; ++ks)
            qf[i][ks] = *(const bf16x8*)(qp + (size_t)(qw + i * 16 + lr) * 128 + ks * 32 + lg * 8);

    f32x4 acc[2][8];
#pragma unroll
    for (int i = 0; i < 2; ++i)
#pragma unroll
        for (int j = 0; j < 8; ++j) acc[i][j] = (f32x4){0.f, 0.f, 0.f, 0.f};
    float mrow[2][4], lrow[2][4];
#pragma unroll
    for (int i = 0; i < 2; ++i)
#pragma unroll
        for (int r = 0; r < 4; ++r) { mrow[i][r] = -1e30f; lrow[i][r] = 0.f; }

    const float scale = 0.08838834764831845f;   // 1/sqrt(128)
    const int nkt = 2 * qt + 2;

    // ---- prologue: stage tile 0 (prior segment's Vt readers already barriered)
    attn_stage_k(kp, 0, &Ks[0][0][0], w, lr, lg);
    VtRegs vr = attn_load_v(vp, 0, tid);
    attn_write_v(Vt, vr, tid);          // vmcnt wait auto-inserted
    __syncthreads();                    // Ks[0] (vmcnt drain) + Vt visible

    int cur = 0;
    for (int kt = 0; kt < nkt; ++kt) {
        const int kbase = kt * 64;
        const bool pf = (kt + 1 < nkt);
        if (pf) {                       // issue next tile's loads BEFORE compute
            attn_stage_k(kp, kbase + 64, &Ks[cur ^ 1][0][0], w, lr, lg);
            vr = attn_load_v(vp, kbase + 64, tid);
        }

        if (kbase <= qw + 31) {
            // ---- S = Q K^T
            f32x4 sc[2][4];
#pragma unroll
            for (int i = 0; i < 2; ++i)
#pragma unroll
                for (int j = 0; j < 4; ++j) sc[i][j] = (f32x4){0.f, 0.f, 0.f, 0.f};
#pragma unroll
            for (int nt = 0; nt < 4; ++nt) {
#pragma unroll
                for (int ks = 0; ks < 4; ++ks) {
                    const int slot = (ks * 4 + lg) ^ (lr & 7);
                    bf16x8 kf = *(const bf16x8*)&Ks[cur][nt * 16 + lr][slot * 8];
#pragma unroll
                    for (int mt = 0; mt < 2; ++mt)
                        sc[mt][nt] = __builtin_amdgcn_mfma_f32_16x16x32_bf16(qf[mt][ks], kf, sc[mt][nt], 0, 0, 0);
                }
            }
            // ---- scale + causal mask
            const bool pm = (kbase + 63 > qw);
#pragma unroll
            for (int mt = 0; mt < 2; ++mt)
#pragma unroll
                for (int nt = 0; nt < 4; ++nt)
#pragma unroll
                    for (int r = 0; r < 4; ++r) {
                        float v = sc[mt][nt][r] * scale;
                        if (pm) {
                            const int qi = qw + mt * 16 + lg * 4 + r;
                            const int ki = kbase + nt * 16 + lr;
                            if (ki > qi) v = -1e30f;
                        }
                        sc[mt][nt][r] = v;
                    }
            // ---- row max (16-lane groups)
            float rm[2][4];
#pragma unroll
            for (int mt = 0; mt < 2; ++mt)
#pragma unroll
                for (int r = 0; r < 4; ++r)
                    rm[mt][r] = fmaxf(fmaxf(sc[mt][0][r], sc[mt][1][r]),
                                      fmaxf(sc[mt][2][r], sc[mt][3][r]));
#pragma unroll
            for (int off = 8; off; off >>= 1)
#pragma unroll
                for (int mt = 0; mt < 2; ++mt)
#pragma unroll
                    for (int r = 0; r < 4; ++r)
                        rm[mt][r] = fmaxf(rm[mt][r], __shfl_xor(rm[mt][r], off, 16));
            // ---- online softmax update
            float fac[2][4];
#pragma unroll
            for (int mt = 0; mt < 2; ++mt)
#pragma unroll
                for (int r = 0; r < 4; ++r) {
                    const float mn = fmaxf(mrow[mt][r], rm[mt][r]);
                    fac[mt][r] = __expf(mrow[mt][r] - mn);
                    mrow[mt][r] = mn;
                    lrow[mt][r] *= fac[mt][r];
                }
#pragma unroll
            for (int mt = 0; mt < 2; ++mt)
#pragma unroll
                for (int nt = 0; nt < 8; ++nt)
#pragma unroll
                    for (int r = 0; r < 4; ++r) acc[mt][nt][r] *= fac[mt][r];
            float rs[2][4] = {{0.f, 0.f, 0.f, 0.f}, {0.f, 0.f, 0.f, 0.f}};
#pragma unroll
            for (int mt = 0; mt < 2; ++mt)
#pragma unroll
                for (int nt = 0; nt < 4; ++nt)
#pragma unroll
                    for (int r = 0; r < 4; ++r) {
                        const float p = __expf(sc[mt][nt][r] - mrow[mt][r]);
                        sc[mt][nt][r] = p;
                        rs[mt][r] += p;
                    }
#pragma unroll
            for (int off = 8; off; off >>= 1)
#pragma unroll
                for (int mt = 0; mt < 2; ++mt)
#pragma unroll
                    for (int r = 0; r < 4; ++r)
                        rs[mt][r] += __shfl_xor(rs[mt][r], off, 16);
#pragma unroll
            for (int mt = 0; mt < 2; ++mt)
#pragma unroll
                for (int r = 0; r < 4; ++r) lrow[mt][r] += rs[mt][r];
            // ---- P -> LDS (per-wave region, no barrier needed)
#pragma unroll
            for (int mt = 0; mt < 2; ++mt)
#pragma unroll
                for (int nt = 0; nt < 4; ++nt)
#pragma unroll
                    for (int r = 0; r < 4; ++r)
                        Psw[mt * 16 + lg * 4 + r][nt * 16 + lr] = f2bf(sc[mt][nt][r]);
            // ---- PV
#pragma unroll
            for (int k2 = 0; k2 < 2; ++k2) {
                bf16x8 pa[2];
                pa[0] = *(const bf16x8*)&Psw[lr][k2 * 32 + lg * 8];
                pa[1] = *(const bf16x8*)&Psw[16 + lr][k2 * 32 + lg * 8];
#pragma unroll
                for (int nt = 0; nt < 8; ++nt) {
                    const int f = ((nt * 2 + (lr >> 3)) ^ lr) & 7;
                    const int slot = (k2 * 4 + lg) ^ f;
                    bf16x8 vb = *(const bf16x8*)&Vt[nt * 16 + lr][slot * 8];
#pragma unroll
                    for (int mt = 0; mt < 2; ++mt)
                        acc[mt][nt] = __builtin_amdgcn_mfma_f32_16x16x32_bf16(pa[mt], vb, acc[mt][nt], 0, 0, 0);
                }
            }
        }

        __syncthreads();                 // all waves done reading Vt / Ks[cur]
        if (pf) attn_write_v(Vt, vr, tid);
        __syncthreads();                 // Vt writes + Ks[cur^1] staging visible
        cur ^= 1;
    }

    // ---- epilogue: y = acc / l
#pragma unroll
    for (int mt = 0; mt < 2; ++mt)
#pragma unroll
        for (int r = 0; r < 4; ++r) {
            const float inv = 1.f / lrow[mt][r];
            const size_t row = qw + mt * 16 + lg * 4 + r;
#pragma unroll
            for (int nt = 0; nt < 8; ++nt)
                yp[row * 2048 + nt * 16 + lr] = f2bf(acc[mt][nt][r] * inv);
        }
}

__global__ __launch_bounds__(256, 2) void k_attn(const u16* __restrict__ qb,
                                                 const u16* __restrict__ kb,
                                                 const u16* __restrict__ qkv,
                                                 u16* __restrict__ yb) {
    __shared__ u16 Ks[2][64][128];   // double-buffered, swizzled 16B slots
    __shared__ u16 Vt[128][64];      // V^T, swizzled
    __shared__ u16 Ps[4][32][72];    // per-wave P, padded

    const int gid = blockIdx.x;
    const int x = gid >> 6;          // pair index 0..7 -> q-tiles (x, 15-x)
    const int g = gid & 63;          // (b,h) group; gid%8 == g%8 -> same XCD
    const int h = g & 15, b = g >> 4;
    const int tid = threadIdx.x;
    const int w = tid >> 6, l = tid & 63;
    const int lr = l & 15, lg = l >> 4;

    const u16* qp = qb + (size_t)((b * 16 + h) * 2048) * 128;
    const u16* kp = kb + (size_t)((b * 16 + h) * 2048) * 128;
    const u16* vp = qkv + (size_t)(b * 2048) * 6144 + 4096 + h * 128;
    u16* yp = yb + (size_t)(b * 2048) * 2048 + h * 128;

    attn_qtile(x,      qp, kp, vp, yp, Ks, Vt, Ps[w], w, lr, lg, tid);
    attn_qtile(15 - x, qp, kp, vp, yp, Ks, Vt, Ps[w], w, lr, lg, tid);
}

// --------------------------------------------------------------------------
extern "C" void kernel_launch(void* const* d_in, const int* in_sizes, int n_in,
                              void* d_out, int out_size, void* d_ws, size_t ws_size,
                              hipStream_t stream) {
    const float* x    = (const float*)d_in[0];
    const float* fcos = (const float*)d_in[1];
    const float* fsin = (const float*)d_in[2];
    const float* Wqkv = (const float*)d_in[3];
    const float* bqkv = (const float*)d_in[4];
    const float* Wout = (const float*)d_in[5];
    const float* bout = (const float*)d_in[6];
    float* out = (float*)d_out;

    if (ws_size < 234881024u) return;   // need 224 MB scratch

    char* ws = (char*)d_ws;
    u16* x_bf  = (u16*)(ws);                 // 32 MB  (aliased later by yb)
    u16* wqkvT = (u16*)(ws + 33554432);      // 24 MB
    u16* woutT = (u16*)(ws + 58720256);      //  8 MB
    u16* qkv   = (u16*)(ws + 67108864);      // 96 MB (q,k,v bf16; v read in-place)
    u16* qb    = (u16*)(ws + 167772160);     // 32 MB
    u16* kb    = (u16*)(ws + 201326592);     // 32 MB
    u16* yb    = x_bf;                       // alias: x_bf dead after GEMM1

    k_cvt_bf16<<<8192, 256, 0, stream>>>(x, x_bf, 2097152);
    k_transpose_bf16<<<dim3(192, 64), 256, 0, stream>>>(Wqkv, wqkvT, 2048, 6144);
    k_transpose_bf16<<<dim3(64, 64), 256, 0, stream>>>(Wout, woutT, 2048, 2048);
    k_gemm_bt<1><<<dim3(64, 48), 256, 0, stream>>>(x_bf, wqkvT, bqkv, qkv, 8192, 6144, 2048);
    k_rope<<<8192, 256, 0, stream>>>(qkv, fcos, fsin, qb, kb);
    k_attn<<<512, 256, 0, stream>>>(qb, kb, qkv, yb);
    k_gemm_bt<0><<<dim3(64, 16), 256, 0, stream>>>(yb, woutT, bout, out, 8192, 2048, 2048);
}

// Round 6
// 555.727 us; speedup vs baseline: 1.2779x; 1.1686x over previous
//
#include <hip/hip_runtime.h>

typedef __attribute__((ext_vector_type(4))) float f32x4;
typedef __attribute__((ext_vector_type(8))) short bf16x8;
typedef __attribute__((ext_vector_type(4))) unsigned int uint4v;
typedef __attribute__((ext_vector_type(4))) unsigned short ushort4v;
typedef unsigned short u16;
typedef unsigned int u32;

#define AS1(p) ((const __attribute__((address_space(1))) u32*)(p))
#define AS3(p) ((__attribute__((address_space(3))) u32*)(p))

__device__ __forceinline__ float bf2f(u16 v) {
    u32 u = ((u32)v) << 16;
    return __builtin_bit_cast(float, u);
}
__device__ __forceinline__ u16 f2bf(float f) {
    u32 u = __builtin_bit_cast(u32, f);
    u += 0x7fffu + ((u >> 16) & 1u);   // RNE
    return (u16)(u >> 16);
}

// ---------------------------------------------------------------- convert x
__global__ __launch_bounds__(256) void k_cvt_bf16(const float* __restrict__ in,
                                                  u16* __restrict__ out, int n8) {
    int t = blockIdx.x * 256 + threadIdx.x;
    if (t >= n8) return;
    const f32x4* p = (const f32x4*)in + (size_t)t * 2;
    f32x4 a = p[0], b = p[1];
    uint4v o;
    o[0] = (u32)f2bf(a[0]) | ((u32)f2bf(a[1]) << 16);
    o[1] = (u32)f2bf(a[2]) | ((u32)f2bf(a[3]) << 16);
    o[2] = (u32)f2bf(b[0]) | ((u32)f2bf(b[1]) << 16);
    o[3] = (u32)f2bf(b[2]) | ((u32)f2bf(b[3]) << 16);
    *((uint4v*)(out + (size_t)t * 8)) = o;
}

// ------------------------------------------- transpose-convert W -> W^T bf16
__global__ __launch_bounds__(256) void k_transpose_bf16(const float* __restrict__ in,
                                                        u16* __restrict__ out,
                                                        int R, int C) {
    __shared__ float tile[32][33];
    const int bx = blockIdx.x * 32, by = blockIdx.y * 32;
    const int tx = threadIdx.x & 31, ty = threadIdx.x >> 5;   // 256 threads
#pragma unroll
    for (int i = 0; i < 32; i += 8)
        tile[ty + i][tx] = in[(size_t)(by + ty + i) * C + bx + tx];
    __syncthreads();
#pragma unroll
    for (int i = 0; i < 32; i += 8)
        out[(size_t)(bx + ty + i) * R + by + tx] = f2bf(tile[tx][ty + i]);
}

// ===================================================== GEMM  C = A*B^T + b
// 256x256 tile, BK=32, 8 waves (2x4), counted-vmcnt 4-deep LDS pipeline.
// LDS layout per operand tile (frag-major, conflict-free, linear-stageable):
//   [group g=row/16][kslot s=k/8][row r][elem e]  (1024 B per 16-row group)
// Ring: 4 buffers; iter t computes buf[t&3], stages tile t+3 -> buf[(t+3)&3].
template <int OUT_BF16>
__global__ __launch_bounds__(512, 2) void k_gemm256(const u16* __restrict__ A,
                                                    const u16* __restrict__ Bt,
                                                    const float* __restrict__ bias,
                                                    void* __restrict__ Cout,
                                                    int M, int N, int K) {
    __shared__ u16 lds[65536];           // A: [4][8192] u16, B: +32768
    const int tid = threadIdx.x;
    const int wid = tid >> 6, l = tid & 63;
    const int lr = l & 15, lg = l >> 4;
    const int wm = wid >> 2, wn = wid & 3;          // 2 x 4 wave grid
    const size_t brow = (size_t)blockIdx.x * 256;
    const size_t bcol = (size_t)blockIdx.y * 256;
    const int KT = K >> 5;                           // BK=32 tiles

    // per-lane global source addrs for staging (lane l -> row l&15, kslot l>>4)
    const int srow = l & 15, scol = (l >> 4) * 8;
    const u16* gA0 = A  + (brow + (size_t)(2 * wid)     * 16 + srow) * K + scol;
    const u16* gA1 = A  + (brow + (size_t)(2 * wid + 1) * 16 + srow) * K + scol;
    const u16* gB0 = Bt + (bcol + (size_t)(2 * wid)     * 16 + srow) * K + scol;
    const u16* gB1 = Bt + (bcol + (size_t)(2 * wid + 1) * 16 + srow) * K + scol;

    f32x4 acc[8][4];
#pragma unroll
    for (int m = 0; m < 8; ++m)
#pragma unroll
        for (int n = 0; n < 4; ++n) acc[m][n] = (f32x4){0.f, 0.f, 0.f, 0.f};

#define STAGE(t)                                                                   \
    {                                                                              \
        const int b_ = (t) & 3;                                                    \
        const int k0_ = (t) << 5;                                                  \
        u16* dA_ = &lds[b_ * 8192 + (2 * wid) * 512];                              \
        u16* dB_ = &lds[32768 + b_ * 8192 + (2 * wid) * 512];                      \
        __builtin_amdgcn_global_load_lds(AS1(gA0 + k0_), AS3(dA_), 16, 0, 0);      \
        __builtin_amdgcn_global_load_lds(AS1(gA1 + k0_), AS3(dA_ + 512), 16, 0, 0);\
        __builtin_amdgcn_global_load_lds(AS1(gB0 + k0_), AS3(dB_), 16, 0, 0);      \
        __builtin_amdgcn_global_load_lds(AS1(gB1 + k0_), AS3(dB_ + 512), 16, 0, 0);\
    }

    // prologue: stage tiles 0,1,2 (12 loads/wave); wait tile 0 (8 remain)
    STAGE(0); STAGE(1); STAGE(2);
    asm volatile("s_waitcnt vmcnt(8)" ::: "memory");
    __builtin_amdgcn_s_barrier();
    __builtin_amdgcn_sched_barrier(0);

#pragma unroll 1
    for (int t = 0; t < KT; ++t) {
        if (t + 3 < KT) STAGE(t + 3);
        const u16* pa = &lds[(t & 3) * 8192 + wm * 4096 + lg * 128 + lr * 8];
        const u16* pb = &lds[32768 + (t & 3) * 8192 + wn * 2048 + lg * 128 + lr * 8];
        bf16x8 af[8], bf[4];
#pragma unroll
        for (int m = 0; m < 8; ++m) af[m] = *(const bf16x8*)(pa + m * 512);
#pragma unroll
        for (int n = 0; n < 4; ++n) bf[n] = *(const bf16x8*)(pb + n * 512);
        __builtin_amdgcn_s_setprio(1);
#pragma unroll
        for (int m = 0; m < 8; ++m)
#pragma unroll
            for (int n = 0; n < 4; ++n)
                acc[m][n] = __builtin_amdgcn_mfma_f32_16x16x32_bf16(af[m], bf[n], acc[m][n], 0, 0, 0);
        __builtin_amdgcn_s_setprio(0);
        __builtin_amdgcn_sched_barrier(0);
        if (t < KT - 3)       asm volatile("s_waitcnt vmcnt(8)" ::: "memory");
        else if (t == KT - 3) asm volatile("s_waitcnt vmcnt(4)" ::: "memory");
        else if (t == KT - 2) asm volatile("s_waitcnt vmcnt(0)" ::: "memory");
        if (t < KT - 1) __builtin_amdgcn_s_barrier();
        __builtin_amdgcn_sched_barrier(0);
    }
#undef STAGE

    // epilogue
    const int crow0 = wm * 128 + lg * 4;
    const int ccol0 = wn * 64 + lr;
#pragma unroll
    for (int m = 0; m < 8; ++m) {
        const size_t row0 = brow + crow0 + m * 16;
#pragma unroll
        for (int n = 0; n < 4; ++n) {
            const size_t col = bcol + ccol0 + n * 16;
            const float bv = bias[col];
#pragma unroll
            for (int r = 0; r < 4; ++r) {
                float v = acc[m][n][r] + bv;
                if (OUT_BF16)
                    ((u16*)Cout)[(row0 + r) * N + col] = f2bf(v);
                else
                    ((float*)Cout)[(row0 + r) * N + col] = v;
            }
        }
    }
}

// ------------------------------------------------------------------- RoPE
// qkv[b][s][6144] bf16 -> qb/kb [b][h][s][128] bf16 (rope applied)
__global__ __launch_bounds__(256) void k_rope(const u16* __restrict__ qkv,
                                              const float* __restrict__ fcos,
                                              const float* __restrict__ fsin,
                                              u16* __restrict__ qb, u16* __restrict__ kb) {
    const int t = blockIdx.x * 256 + threadIdx.x;
    const int e = t & 7, h = (t >> 3) & 15, r = (t >> 7) & 1, s = (t >> 8) & 2047, b = t >> 19;
    const u16* src = qkv + ((size_t)(b * 2048 + s)) * 6144 + r * 2048 + h * 128 + e * 16;
    uint4v p0 = *(const uint4v*)src;
    uint4v p1 = *(const uint4v*)(src + 8);
    const float* cp = fcos + s * 64 + e * 8;
    const float* sp = fsin + s * 64 + e * 8;
    f32x4 c0 = *(const f32x4*)cp, c1 = *(const f32x4*)(cp + 4);
    f32x4 s0 = *(const f32x4*)sp, s1 = *(const f32x4*)(sp + 4);
    float x[16];
#pragma unroll
    for (int i = 0; i < 4; ++i) {
        x[2 * i]     = bf2f((u16)(p0[i] & 0xffff));
        x[2 * i + 1] = bf2f((u16)(p0[i] >> 16));
        x[8 + 2 * i]     = bf2f((u16)(p1[i] & 0xffff));
        x[8 + 2 * i + 1] = bf2f((u16)(p1[i] >> 16));
    }
    float c[8]  = {c0[0], c0[1], c0[2], c0[3], c1[0], c1[1], c1[2], c1[3]};
    float sn[8] = {s0[0], s0[1], s0[2], s0[3], s1[0], s1[1], s1[2], s1[3]};
    u32 ow[8];
#pragma unroll
    for (int i = 0; i < 8; ++i) {
        float xr = x[2 * i], xi = x[2 * i + 1];
        float orr = xr * c[i] - xi * sn[i];
        float oii = xr * sn[i] + xi * c[i];
        ow[i] = (u32)f2bf(orr) | ((u32)f2bf(oii) << 16);
    }
    u16* dst = (r ? kb : qb) + ((size_t)((b * 16 + h) * 2048 + s)) * 128 + e * 16;
    uint4v q0 = {ow[0], ow[1], ow[2], ow[3]};
    uint4v q1 = {ow[4], ow[5], ow[6], ow[7]};
    *(uint4v*)dst = q0;
    *(uint4v*)(dst + 8) = q1;
}

// ------------------------------------------------- causal flash attention
// Pipelined: double-buffered K (global_load_lds), reg-split V staging (T14),
// paired q-tiles (x, 15-x) per block, XCD-locality block mapping.
struct VtRegs { uint4v v0, v1, v2, v3; };

__device__ __forceinline__ void attn_stage_k(const u16* kp, int kbase, u16* dstBase,
                                             int w, int lr, int lg) {
#pragma unroll
    for (int c = 0; c < 4; ++c) {
        const int row = w * 16 + c * 4 + lg;
        const int sslot = lr ^ (4 * (c & 1) + lg);           // inverse swizzle on source
        const u16* gsrc = kp + (size_t)(kbase + row) * 128 + sslot * 8;
        __builtin_amdgcn_global_load_lds(AS1(gsrc), AS3(dstBase + (w * 16 + c * 4) * 128), 16, 0, 0);
    }
}

__device__ __forceinline__ VtRegs attn_load_v(const u16* vp, int kbase, int tid) {
    const int rg = tid >> 4, cg = tid & 15;
    const u16* gv = vp + (size_t)(kbase + rg * 4) * 6144 + cg * 8;
    VtRegs r;
    r.v0 = *(const uint4v*)gv;
    r.v1 = *(const uint4v*)(gv + 6144);
    r.v2 = *(const uint4v*)(gv + 2 * 6144);
    r.v3 = *(const uint4v*)(gv + 3 * 6144);
    return r;
}

__device__ __forceinline__ void attn_write_v(u16 (*Vt)[64], const VtRegs& r, int tid) {
    const int rg = tid >> 4, cg = tid & 15;
    const u16* u0 = (const u16*)&r.v0;
    const u16* u1 = (const u16*)&r.v1;
    const u16* u2 = (const u16*)&r.v2;
    const u16* u3 = (const u16*)&r.v3;
    const int sb = rg >> 1, hf = (rg & 1) * 4;
#pragma unroll
    for (int cc = 0; cc < 8; ++cc) {
        const int row = cg * 8 + cc;                          // hd index
        const int col = ((sb ^ ((cg ^ cc) & 7)) << 3) + hf;   // swizzled seq slot
        ushort4v pk = {u0[cc], u1[cc], u2[cc], u3[cc]};
        *(ushort4v*)&Vt[row][col] = pk;
    }
}

__device__ __forceinline__ void attn_qtile(int qt, const u16* qp, const u16* kp,
                                           const u16* vp, u16* yp,
                                           u16 (*Ks)[64][128], u16 (*Vt)[64],
                                           u16 (*Psw)[72],
                                           int w, int lr, int lg, int tid) {
    const int qw = qt * 128 + w * 32;

    bf16x8 qf[2][4];
#pragma unroll
    for (int i = 0; i < 2; ++i)
#pragma unroll
        for (int ks = 0; ks < 4; ++ks)
            qf[i][ks] = *(const bf16x8*)(qp + (size_t)(qw + i * 16 + lr) * 128 + ks * 32 + lg * 8);

    f32x4 acc[2][8];
#pragma unroll
    for (int i = 0; i < 2; ++i)
#pragma unroll
        for (int j = 0; j < 8; ++j) acc[i][j] = (f32x4){0.f, 0.f, 0.f, 0.f};
    float mrow[2][4], lrow[2][4];
#pragma unroll
    for (int i = 0; i < 2; ++i)
#pragma unroll
        for (int r = 0; r < 4; ++r) { mrow[i][r] = -1e30f; lrow[i][r] = 0.f; }

    const float scale = 0.08838834764831845f;   // 1/sqrt(128)
    const int nkt = 2 * qt + 2;

    // ---- prologue: stage tile 0
    attn_stage_k(kp, 0, &Ks[0][0][0], w, lr, lg);
    VtRegs vr = attn_load_v(vp, 0, tid);
    attn_write_v(Vt, vr, tid);          // vmcnt wait auto-inserted
    __syncthreads();                    // Ks[0] (vmcnt drain) + Vt visible

    int cur = 0;
    for (int kt = 0; kt < nkt; ++kt) {
        const int kbase = kt * 64;
        const bool pf = (kt + 1 < nkt);
        if (pf) {                       // issue next tile's loads BEFORE compute
            attn_stage_k(kp, kbase + 64, &Ks[cur ^ 1][0][0], w, lr, lg);
            vr = attn_load_v(vp, kbase + 64, tid);
        }

        if (kbase <= qw + 31) {
            // ---- S = Q K^T
            f32x4 sc[2][4];
#pragma unroll
            for (int i = 0; i < 2; ++i)
#pragma unroll
                for (int j = 0; j < 4; ++j) sc[i][j] = (f32x4){0.f, 0.f, 0.f, 0.f};
#pragma unroll
            for (int nt = 0; nt < 4; ++nt) {
#pragma unroll
                for (int ks = 0; ks < 4; ++ks) {
                    const int slot = (ks * 4 + lg) ^ (lr & 7);
                    bf16x8 kf = *(const bf16x8*)&Ks[cur][nt * 16 + lr][slot * 8];
#pragma unroll
                    for (int mt = 0; mt < 2; ++mt)
                        sc[mt][nt] = __builtin_amdgcn_mfma_f32_16x16x32_bf16(qf[mt][ks], kf, sc[mt][nt], 0, 0, 0);
                }
            }
            // ---- scale + causal mask
            const bool pm = (kbase + 63 > qw);
#pragma unroll
            for (int mt = 0; mt < 2; ++mt)
#pragma unroll
                for (int nt = 0; nt < 4; ++nt)
#pragma unroll
                    for (int r = 0; r < 4; ++r) {
                        float v = sc[mt][nt][r] * scale;
                        if (pm) {
                            const int qi = qw + mt * 16 + lg * 4 + r;
                            const int ki = kbase + nt * 16 + lr;
                            if (ki > qi) v = -1e30f;
                        }
                        sc[mt][nt][r] = v;
                    }
            // ---- row max (16-lane groups)
            float rm[2][4];
#pragma unroll
            for (int mt = 0; mt < 2; ++mt)
#pragma unroll
                for (int r = 0; r < 4; ++r)
                    rm[mt][r] = fmaxf(fmaxf(sc[mt][0][r], sc[mt][1][r]),
                                      fmaxf(sc[mt][2][r], sc[mt][3][r]));
#pragma unroll
            for (int off = 8; off; off >>= 1)
#pragma unroll
                for (int mt = 0; mt < 2; ++mt)
#pragma unroll
                    for (int r = 0; r < 4; ++r)
                        rm[mt][r] = fmaxf(rm[mt][r], __shfl_xor(rm[mt][r], off, 16));
            // ---- online softmax update
            float fac[2][4];
#pragma unroll
            for (int mt = 0; mt < 2; ++mt)
#pragma unroll
                for (int r = 0; r < 4; ++r) {
                    const float mn = fmaxf(mrow[mt][r], rm[mt][r]);
                    fac[mt][r] = __expf(mrow[mt][r] - mn);
                    mrow[mt][r] = mn;
                    lrow[mt][r] *= fac[mt][r];
                }
#pragma unroll
            for (int mt = 0; mt < 2; ++mt)
#pragma unroll
                for (int nt = 0; nt < 8; ++nt)
#pragma unroll
                    for (int r = 0; r < 4; ++r) acc[mt][nt][r] *= fac[mt][r];
            float rs[2][4] = {{0.f, 0.f, 0.f, 0.f}, {0.f, 0.f, 0.f, 0.f}};
#pragma unroll
            for (int mt = 0; mt < 2; ++mt)
#pragma unroll
                for (int nt = 0; nt < 4; ++nt)
#pragma unroll
                    for (int r = 0; r < 4; ++r) {
                        const float p = __expf(sc[mt][nt][r] - mrow[mt][r]);
                        sc[mt][nt][r] = p;
                        rs[mt][r] += p;
                    }
#pragma unroll
            for (int off = 8; off; off >>= 1)
#pragma unroll
                for (int mt = 0; mt < 2; ++mt)
#pragma unroll
                    for (int r = 0; r < 4; ++r)
                        rs[mt][r] += __shfl_xor(rs[mt][r], off, 16);
#pragma unroll
            for (int mt = 0; mt < 2; ++mt)
#pragma unroll
                for (int r = 0; r < 4; ++r) lrow[mt][r] += rs[mt][r];
            // ---- P -> LDS (per-wave region, no barrier needed)
#pragma unroll
            for (int mt = 0; mt < 2; ++mt)
#pragma unroll
                for (int nt = 0; nt < 4; ++nt)
#pragma unroll
                    for (int r = 0; r < 4; ++r)
                        Psw[mt * 16 + lg * 4 + r][nt * 16 + lr] = f2bf(sc[mt][nt][r]);
            // ---- PV
#pragma unroll
            for (int k2 = 0; k2 < 2; ++k2) {
                bf16x8 pa[2];
                pa[0] = *(const bf16x8*)&Psw[lr][k2 * 32 + lg * 8];
                pa[1] = *(const bf16x8*)&Psw[16 + lr][k2 * 32 + lg * 8];
#pragma unroll
                for (int nt = 0; nt < 8; ++nt) {
                    const int f = ((nt * 2 + (lr >> 3)) ^ lr) & 7;
                    const int slot = (k2 * 4 + lg) ^ f;
                    bf16x8 vb = *(const bf16x8*)&Vt[nt * 16 + lr][slot * 8];
#pragma unroll
                    for (int mt = 0; mt < 2; ++mt)
                        acc[mt][nt] = __builtin_amdgcn_mfma_f32_16x16x32_bf16(pa[mt], vb, acc[mt][nt], 0, 0, 0);
                }
            }
        }

        __syncthreads();                 // all waves done reading Vt / Ks[cur]
        if (pf) attn_write_v(Vt, vr, tid);
        __syncthreads();                 // Vt writes + Ks[cur^1] staging visible
        cur ^= 1;
    }

    // ---- epilogue: y = acc / l
#pragma unroll
    for (int mt = 0; mt < 2; ++mt)
#pragma unroll
        for (int r = 0; r < 4; ++r) {
            const float inv = 1.f / lrow[mt][r];
            const size_t row = qw + mt * 16 + lg * 4 + r;
#pragma unroll
            for (int nt = 0; nt < 8; ++nt)
                yp[row * 2048 + nt * 16 + lr] = f2bf(acc[mt][nt][r] * inv);
        }
}

__global__ __launch_bounds__(256, 2) void k_attn(const u16* __restrict__ qb,
                                                 const u16* __restrict__ kb,
                                                 const u16* __restrict__ qkv,
                                                 u16* __restrict__ yb) {
    __shared__ u16 Ks[2][64][128];   // double-buffered, swizzled 16B slots
    __shared__ u16 Vt[128][64];      // V^T, swizzled
    __shared__ u16 Ps[4][32][72];    // per-wave P, padded

    const int gid = blockIdx.x;
    const int x = gid >> 6;          // pair index 0..7 -> q-tiles (x, 15-x)
    const int g = gid & 63;          // (b,h) group; gid%8 == g%8 -> same XCD
    const int h = g & 15, b = g >> 4;
    const int tid = threadIdx.x;
    const int w = tid >> 6, l = tid & 63;
    const int lr = l & 15, lg = l >> 4;

    const u16* qp = qb + (size_t)((b * 16 + h) * 2048) * 128;
    const u16* kp = kb + (size_t)((b * 16 + h) * 2048) * 128;
    const u16* vp = qkv + (size_t)(b * 2048) * 6144 + 4096 + h * 128;
    u16* yp = yb + (size_t)(b * 2048) * 2048 + h * 128;

    attn_qtile(x,      qp, kp, vp, yp, Ks, Vt, Ps[w], w, lr, lg, tid);
    attn_qtile(15 - x, qp, kp, vp, yp, Ks, Vt, Ps[w], w, lr, lg, tid);
}

// --------------------------------------------------------------------------
extern "C" void kernel_launch(void* const* d_in, const int* in_sizes, int n_in,
                              void* d_out, int out_size, void* d_ws, size_t ws_size,
                              hipStream_t stream) {
    const float* x    = (const float*)d_in[0];
    const float* fcos = (const float*)d_in[1];
    const float* fsin = (const float*)d_in[2];
    const float* Wqkv = (const float*)d_in[3];
    const float* bqkv = (const float*)d_in[4];
    const float* Wout = (const float*)d_in[5];
    const float* bout = (const float*)d_in[6];
    float* out = (float*)d_out;

    if (ws_size < 234881024u) return;   // need 224 MB scratch

    char* ws = (char*)d_ws;
    u16* x_bf  = (u16*)(ws);                 // 32 MB  (aliased later by yb)
    u16* wqkvT = (u16*)(ws + 33554432);      // 24 MB
    u16* woutT = (u16*)(ws + 58720256);      //  8 MB
    u16* qkv   = (u16*)(ws + 67108864);      // 96 MB (q,k,v bf16; v read in-place)
    u16* qb    = (u16*)(ws + 167772160);     // 32 MB
    u16* kb    = (u16*)(ws + 201326592);     // 32 MB
    u16* yb    = x_bf;                       // alias: x_bf dead after GEMM1

    k_cvt_bf16<<<8192, 256, 0, stream>>>(x, x_bf, 2097152);
    k_transpose_bf16<<<dim3(192, 64), 256, 0, stream>>>(Wqkv, wqkvT, 2048, 6144);
    k_transpose_bf16<<<dim3(64, 64), 256, 0, stream>>>(Wout, woutT, 2048, 2048);
    k_gemm256<1><<<dim3(32, 24), 512, 0, stream>>>(x_bf, wqkvT, bqkv, qkv, 8192, 6144, 2048);
    k_rope<<<8192, 256, 0, stream>>>(qkv, fcos, fsin, qb, kb);
    k_attn<<<512, 256, 0, stream>>>(qb, kb, qkv, yb);
    k_gemm256<0><<<dim3(32, 8), 512, 0, stream>>>(yb, woutT, bout, out, 8192, 2048, 2048);
}